// Round 1
// baseline (132.173 us; speedup 1.0000x reference)
//
#include <hip/hip_runtime.h>
#include <hip/hip_bf16.h>

typedef unsigned int u32;
typedef __attribute__((ext_vector_type(8))) _Float16 f16x8;
typedef __attribute__((ext_vector_type(4))) float f32x4;

#define GMIN_ 0.01f
#define GMAX_ 10.0f

// ---------------------------------------------------------------------------
// Prep: theta_[258][256] f32  ->  W2t f16 [256 cols][512 K-interleaved]
//                                 bias f32 [256]
// K-interleave: W2t[n][2k]   = Wp[k][n]  (pos branch, pairs with a)
//               W2t[n][2k+1] = Wn[k][n]  (neg branch, pairs with aneg)
// Row 256 (ones) folded into bias; row 257 (zeros) contributes nothing
// (but its |theta| IS in the normalization sum).
// ---------------------------------------------------------------------------
__global__ __launch_bounds__(256) void prep_weights(
    const float* __restrict__ theta, const float* __restrict__ eta_inv,
    _Float16* __restrict__ W2t, float* __restrict__ bias)
{
    __shared__ float psum[16][16];
    const int t    = threadIdx.x;
    const int nloc = t & 15;
    const int kth  = t >> 4;              // 0..15
    const int n    = blockIdx.x * 16 + nloc;

    // pass 1: column sum of |clamped,thresholded theta| over all 258 rows
    float partial = 0.f;
    for (int k = kth; k < 258; k += 16) {
        float tt = theta[k * 256 + n];
        tt = fminf(fmaxf(tt, -GMAX_), GMAX_);
        if (fabsf(tt) < GMIN_) tt = 0.f;
        partial += fabsf(tt);
    }
    psum[kth][nloc] = partial;
    __syncthreads();
    float s = 0.f;
#pragma unroll
    for (int j = 0; j < 16; ++j) s += psum[j][nloc];
    const float inv = 1.0f / s;

    // pass 2: write interleaved f16 weights (rows 0..255)
    for (int k = kth; k < 256; k += 16) {
        float tt = theta[k * 256 + n];
        tt = fminf(fmaxf(tt, -GMAX_), GMAX_);
        if (fabsf(tt) < GMIN_) tt = 0.f;
        float w  = fabsf(tt) * inv;
        float wp = (tt >= 0.f) ? w : 0.f;
        float wn = w - wp;
        union { _Float16 h[2]; u32 u; } p;
        p.h[0] = (_Float16)wp;
        p.h[1] = (_Float16)wn;
        *(u32*)((char*)W2t + (size_t)n * 1024 + (size_t)k * 4) = p.u;
    }

    // row 256 -> f32 bias (dominant term, stays full precision)
    if (kth == 0) {
        float tt = theta[256 * 256 + n];
        tt = fminf(fmaxf(tt, -GMAX_), GMAX_);
        if (fabsf(tt) < GMIN_) tt = 0.f;
        float w  = fabsf(tt) * inv;
        float wp = (tt >= 0.f) ? w : 0.f;
        float wn = w - wp;
        float ei0 = eta_inv[0], ei1 = eta_inv[1], ei2 = eta_inv[2], ei3 = eta_inv[3];
        float a1 = ei0 + ei1 * tanhf((1.0f - ei2) * ei3);  // ptanh(1, eta_inv)
        bias[n] = wp + a1 * wn;
    }
}

// ---------------------------------------------------------------------------
// GEMM: out[b][n] = ptanh_act( bias[n] + sum_k A2[b][k] * W2t[n][k] )
// A2[b][2c]=f16(a[b][c]), A2[b][2c+1]=f16(ptanh_inv(a[b][c])), K=512.
// BM=128 BN=128 BK=64(f16) ; 4 waves, each 64x64 via 16x16x32 f16 MFMA.
// A: reg-staged (f32->tanh->f16 pack) + XOR-swizzled ds_write_b128.
// B: global_load_lds dwordx4 with pre-swizzled global source.
// ---------------------------------------------------------------------------
__global__ __launch_bounds__(256) void plax_gemm(
    const float* __restrict__ A, const _Float16* __restrict__ W2t,
    const float* __restrict__ bias, const float* __restrict__ eta_act,
    const float* __restrict__ eta_inv, float* __restrict__ out)
{
    __shared__ __align__(16) char lds[32768];   // As [128][64] f16 | Bs [128][64] f16
    char* ldsB = lds + 16384;

    const int t    = threadIdx.x;
    const int bid  = blockIdx.x;
    const int sw   = ((bid & 7) << 6) | (bid >> 3);   // XCD-bijective (512 % 8 == 0)
    const int bm   = sw >> 1;                         // 0..255
    const int bn   = sw & 1;                          // 0..1
    const int lane = t & 63;
    const int wave = t >> 6;
    const int wr   = wave >> 1, wc = wave & 1;

    const float ei0 = eta_inv[0], ei1 = eta_inv[1], ei2 = eta_inv[2], ei3 = eta_inv[3];

    f32x4 acc[4][4] = {};

    const int r0 = t >> 3;        // 0..31 (A-stage row base)
    const int c4 = t & 7;         // float4 column / 16B slot

    for (int kt = 0; kt < 8; ++kt) {
        __syncthreads();          // previous compute done before overwrite

        // ---- B stage: 16KB via global_load_lds, source pre-swizzled ----
#pragma unroll
        for (int i = 0; i < 4; ++i) {
            const int o  = i * 4096 + t * 16;        // linear LDS offset
            const int r  = o >> 7;                   // n-local row
            const int sl = (o >> 4) & 7;             // physical 16B slot
            const int s0 = sl ^ (r & 7);             // logical slot to fetch
            const char* gp = (const char*)W2t
                + (size_t)(bn * 128 + r) * 1024 + (size_t)kt * 128 + (size_t)s0 * 16;
            __builtin_amdgcn_global_load_lds(
                (const __attribute__((address_space(1))) u32*)gp,
                (__attribute__((address_space(3))) u32*)(ldsB + o), 16, 0, 0);
        }

        // ---- A stage: load f32x4, compute inverter act, pack interleaved f16 ----
#pragma unroll
        for (int i = 0; i < 4; ++i) {
            const int r = r0 + 32 * i;
            const float4 v = *(const float4*)&A[(size_t)(bm * 128 + r) * 256 + kt * 32 + c4 * 4];
            f16x8 hv;
            const float xs0 = v.x, xs1 = v.y, xs2 = v.z, xs3 = v.w;
            hv[0] = (_Float16)xs0; hv[1] = (_Float16)(ei0 + ei1 * tanhf((xs0 - ei2) * ei3));
            hv[2] = (_Float16)xs1; hv[3] = (_Float16)(ei0 + ei1 * tanhf((xs1 - ei2) * ei3));
            hv[4] = (_Float16)xs2; hv[5] = (_Float16)(ei0 + ei1 * tanhf((xs2 - ei2) * ei3));
            hv[6] = (_Float16)xs3; hv[7] = (_Float16)(ei0 + ei1 * tanhf((xs3 - ei2) * ei3));
            const int s0 = c4 ^ (r & 7);
            *(f16x8*)(lds + (size_t)r * 128 + s0 * 16) = hv;
        }

        __syncthreads();          // staging visible to all waves

        // ---- compute: 2 k-substeps x 16 MFMA ----
#pragma unroll
        for (int ks = 0; ks < 2; ++ks) {
            f16x8 af[4], bf[4];
#pragma unroll
            for (int m = 0; m < 4; ++m) {
                const int rr   = wr * 64 + m * 16 + (lane & 15);
                const int slot = (ks * 4 + (lane >> 4)) ^ (rr & 7);
                af[m] = *(const f16x8*)(lds + (size_t)rr * 128 + slot * 16);
            }
#pragma unroll
            for (int nn = 0; nn < 4; ++nn) {
                const int rr   = wc * 64 + nn * 16 + (lane & 15);
                const int slot = (ks * 4 + (lane >> 4)) ^ (rr & 7);
                bf[nn] = *(const f16x8*)(ldsB + (size_t)rr * 128 + slot * 16);
            }
#pragma unroll
            for (int m = 0; m < 4; ++m)
#pragma unroll
                for (int nn = 0; nn < 4; ++nn)
                    acc[m][nn] = __builtin_amdgcn_mfma_f32_16x16x32_f16(
                        af[m], bf[nn], acc[m][nn], 0, 0, 0);
        }
    }

    // ---- epilogue: z = acc + bias ; out = ptanh_act(z) ----
    const float ea0 = eta_act[0], ea1 = eta_act[1], ea2 = eta_act[2], ea3 = eta_act[3];
    const int colbase = bn * 128 + wc * 64 + (lane & 15);
    float bcol[4];
#pragma unroll
    for (int nn = 0; nn < 4; ++nn) bcol[nn] = bias[colbase + nn * 16];

#pragma unroll
    for (int m = 0; m < 4; ++m) {
        const int rgb = bm * 128 + wr * 64 + m * 16 + (lane >> 4) * 4;
#pragma unroll
        for (int nn = 0; nn < 4; ++nn) {
            const int cg = colbase + nn * 16;
#pragma unroll
            for (int j = 0; j < 4; ++j) {
                const float z = acc[m][nn][j] + bcol[nn];
                out[(size_t)(rgb + j) * 256 + cg] = ea0 + ea1 * tanhf((z - ea2) * ea3);
            }
        }
    }
}

// ---------------------------------------------------------------------------
extern "C" void kernel_launch(void* const* d_in, const int* in_sizes, int n_in,
                              void* d_out, int out_size, void* d_ws, size_t ws_size,
                              hipStream_t stream) {
    (void)in_sizes; (void)n_in; (void)out_size; (void)ws_size;
    const float* a       = (const float*)d_in[0];
    const float* theta   = (const float*)d_in[1];
    const float* eta_act = (const float*)d_in[2];
    const float* eta_inv = (const float*)d_in[3];
    float* out = (float*)d_out;

    _Float16* W2t = (_Float16*)d_ws;                        // 256*512*2 = 256 KiB
    float*    bias = (float*)((char*)d_ws + 256 * 512 * 2); // 1 KiB

    prep_weights<<<16, 256, 0, stream>>>(theta, eta_inv, W2t, bias);
    plax_gemm<<<512, 256, 0, stream>>>(a, W2t, bias, eta_act, eta_inv, out);
}

// Round 4
// 129.172 us; speedup vs baseline: 1.0232x; 1.0232x over previous
//
#include <hip/hip_runtime.h>
#include <hip/hip_bf16.h>

typedef unsigned int u32;
typedef __attribute__((ext_vector_type(8))) _Float16 f16x8;
typedef __attribute__((ext_vector_type(4))) float f32x4;

#define GMIN_ 0.01f
#define GMAX_ 10.0f

// fast tanh(y) given y2 = 2*y :  tanh(y) = 1 - 2/(exp(2y)+1)
// __expf -> v_exp_f32 path; rcp -> v_rcp_f32. |err| ~1e-6, well inside budget.
__device__ __forceinline__ float tanh_fast2(float y2) {
    float e = __expf(y2);
    float r = __builtin_amdgcn_rcpf(e + 1.0f);
    return fmaf(-2.0f, r, 1.0f);
}

// ---------------------------------------------------------------------------
// Prep: one block per output column n. theta col read once, kept in register.
// W2t f16 [256 cols][512], K-interleaved: [2k]=wp(k) (pairs a), [2k+1]=wn(k)
// (pairs aneg). Row 256 folded into f32 bias; row 257 only feeds the norm sum.
// ---------------------------------------------------------------------------
__global__ __launch_bounds__(256) void prep_weights(
    const float* __restrict__ theta, const float* __restrict__ eta_inv,
    _Float16* __restrict__ W2t, float* __restrict__ bias)
{
    const int n = blockIdx.x;       // column
    const int t = threadIdx.x;      // row
    const int lane = t & 63, wave = t >> 6;
    __shared__ float red[4];

    float tt = theta[t * 256 + n];
    tt = fminf(fmaxf(tt, -GMAX_), GMAX_);
    if (fabsf(tt) < GMIN_) tt = 0.f;

    float extra = 0.f;
    if (t < 2) {
        extra = theta[(256 + t) * 256 + n];
        extra = fminf(fmaxf(extra, -GMAX_), GMAX_);
        if (fabsf(extra) < GMIN_) extra = 0.f;
    }

    float s = fabsf(tt) + fabsf(extra);
#pragma unroll
    for (int i = 32; i > 0; i >>= 1) s += __shfl_xor(s, i);
    if (lane == 0) red[wave] = s;
    __syncthreads();
    const float inv = 1.0f / (red[0] + red[1] + red[2] + red[3]);

    const float w  = fabsf(tt) * inv;
    const float wp = (tt >= 0.f) ? w : 0.f;
    const float wn = w - wp;
    union { _Float16 h[2]; u32 u; } p;
    p.h[0] = (_Float16)wp;
    p.h[1] = (_Float16)wn;
    *(u32*)((char*)W2t + (size_t)n * 1024 + (size_t)t * 4) = p.u;  // coalesced

    if (t == 0) {
        const float w6  = fabsf(extra) * inv;   // extra == row 256 value
        const float wp6 = (extra >= 0.f) ? w6 : 0.f;
        const float wn6 = w6 - wp6;
        const float ei0 = eta_inv[0], ei1 = eta_inv[1], ei2 = eta_inv[2], ei3 = eta_inv[3];
        const float a1  = ei0 + ei1 * tanhf((1.0f - ei2) * ei3);   // ptanh(1, eta_inv)
        bias[n] = wp6 + a1 * wn6;
    }
}

// ---------------------------------------------------------------------------
// Zero-LDS, zero-barrier GEMM.
// Block = 4 waves stacked over m; wave owns 32 rows x 64 cols.
// Per ks (K16=32 f16): A frags direct from global (f32 -> tanh -> f16 pack in
// regs), B frags direct from L2-resident W2t. 1-deep register pipeline.
// Grid = 256 mblk x 4 nblk = 1024 blocks (4 blocks/CU).
// ---------------------------------------------------------------------------
__global__ __launch_bounds__(256, 4) void plax_gemm(
    const float* __restrict__ A, const _Float16* __restrict__ W2t,
    const float* __restrict__ bias, const float* __restrict__ eta_act,
    const float* __restrict__ eta_inv, float* __restrict__ out)
{
    const int t    = threadIdx.x;
    const int bid  = blockIdx.x;
    // XCD chunks of 128 blocks; within a chunk nblk varies fastest so the 4
    // n-blocks sharing A-rows are co-resident on one XCD's L2. 1024 % 8 == 0.
    const int swz  = ((bid & 7) << 7) | (bid >> 3);
    const int mblk = swz >> 2;       // 0..255
    const int nblk = swz & 3;        // 0..3
    const int lane = t & 63, wave = t >> 6;
    const int lr   = lane & 15, lg = lane >> 4;

    const float ei0 = eta_inv[0], ei1 = eta_inv[1];
    const float k2i = 2.0f * eta_inv[3];
    const float c2i = 2.0f * eta_inv[2] * eta_inv[3];

    const int row0 = mblk * 128 + wave * 32;
    const int col0 = nblk * 64;

    const float*    ap = A   + (size_t)(row0 + lr) * 256 + lg * 4;
    const _Float16* bp = W2t + (size_t)(col0 + lr) * 512 + lg * 8;

    f32x4 acc[2][4] = {};

#define LD(ks, aa, bb) do {                                   \
        aa[0] = *(const float4*)(ap + (ks) * 16);             \
        aa[1] = *(const float4*)(ap + 4096 + (ks) * 16);      \
        bb[0] = *(const f16x8*)(bp + (ks) * 32);              \
        bb[1] = *(const f16x8*)(bp + 8192  + (ks) * 32);      \
        bb[2] = *(const f16x8*)(bp + 16384 + (ks) * 32);      \
        bb[3] = *(const f16x8*)(bp + 24576 + (ks) * 32);      \
    } while (0)

    float4 a4c[2]; f16x8 bfc[4];
    LD(0, a4c, bfc);

#pragma unroll
    for (int ks = 0; ks < 16; ++ks) {
        float4 a4n[2]; f16x8 bfn[4];
        if (ks < 15) LD(ks + 1, a4n, bfn);   // prefetch next slice

        f16x8 af[2];
#pragma unroll
        for (int m = 0; m < 2; ++m) {
            const float4 v = a4c[m];
            f16x8 h;
            h[0] = (_Float16)v.x;
            h[1] = (_Float16)fmaf(ei1, tanh_fast2(fmaf(v.x, k2i, -c2i)), ei0);
            h[2] = (_Float16)v.y;
            h[3] = (_Float16)fmaf(ei1, tanh_fast2(fmaf(v.y, k2i, -c2i)), ei0);
            h[4] = (_Float16)v.z;
            h[5] = (_Float16)fmaf(ei1, tanh_fast2(fmaf(v.z, k2i, -c2i)), ei0);
            h[6] = (_Float16)v.w;
            h[7] = (_Float16)fmaf(ei1, tanh_fast2(fmaf(v.w, k2i, -c2i)), ei0);
            af[m] = h;
        }

#pragma unroll
        for (int m = 0; m < 2; ++m)
#pragma unroll
            for (int n = 0; n < 4; ++n)
                acc[m][n] = __builtin_amdgcn_mfma_f32_16x16x32_f16(
                    af[m], bfc[n], acc[m][n], 0, 0, 0);

        if (ks < 15) {
#pragma unroll
            for (int m = 0; m < 2; ++m) a4c[m] = a4n[m];
#pragma unroll
            for (int n = 0; n < 4; ++n) bfc[n] = bfn[n];
        }
    }
#undef LD

    // ---- epilogue: z = acc + bias ; out = ptanh_act(z) ----
    const float ea0 = eta_act[0], ea1 = eta_act[1];
    const float k2a = 2.0f * eta_act[3];
    const float c2a = 2.0f * eta_act[2] * eta_act[3];

    float bc[4];
#pragma unroll
    for (int n = 0; n < 4; ++n) bc[n] = bias[col0 + n * 16 + lr];

#pragma unroll
    for (int m = 0; m < 2; ++m) {
        const int rgb = row0 + m * 16 + lg * 4;
#pragma unroll
        for (int n = 0; n < 4; ++n) {
            const int cg = col0 + n * 16 + lr;
#pragma unroll
            for (int j = 0; j < 4; ++j) {
                const float z = acc[m][n][j] + bc[n];
                out[(size_t)(rgb + j) * 256 + cg] =
                    fmaf(ea1, tanh_fast2(fmaf(z, k2a, -c2a)), ea0);
            }
        }
    }
}

// ---------------------------------------------------------------------------
extern "C" void kernel_launch(void* const* d_in, const int* in_sizes, int n_in,
                              void* d_out, int out_size, void* d_ws, size_t ws_size,
                              hipStream_t stream) {
    (void)in_sizes; (void)n_in; (void)out_size; (void)ws_size;
    const float* a       = (const float*)d_in[0];
    const float* theta   = (const float*)d_in[1];
    const float* eta_act = (const float*)d_in[2];
    const float* eta_inv = (const float*)d_in[3];
    float* out = (float*)d_out;

    _Float16* W2t  = (_Float16*)d_ws;                        // 256*512*2 = 256 KiB
    float*    bias = (float*)((char*)d_ws + 256 * 512 * 2);  // 1 KiB

    prep_weights<<<256, 256, 0, stream>>>(theta, eta_inv, W2t, bias);
    plax_gemm<<<1024, 256, 0, stream>>>(a, W2t, bias, eta_act, eta_inv, out);
}

// Round 5
// 106.281 us; speedup vs baseline: 1.2436x; 1.2154x over previous
//
#include <hip/hip_runtime.h>
#include <hip/hip_bf16.h>

typedef unsigned int u32;
typedef __attribute__((ext_vector_type(8))) _Float16 f16x8;
typedef __attribute__((ext_vector_type(4))) float f32x4;

#define GMIN_ 0.01f
#define GMAX_ 10.0f

// fast tanh(y) given y2 = 2*y :  tanh(y) = 1 - 2/(exp(2y)+1)
__device__ __forceinline__ float tanh_fast2(float y2) {
    float e = __expf(y2);
    float r = __builtin_amdgcn_rcpf(e + 1.0f);
    return fmaf(-2.0f, r, 1.0f);
}

// ---------------------------------------------------------------------------
// Prep (unchanged from R4, passed): W2t f16 [256 cols][512 K-interleaved],
// [2k]=wp(k) pairs a, [2k+1]=wn(k) pairs aneg. Row 256 -> f32 bias.
// ---------------------------------------------------------------------------
__global__ __launch_bounds__(256) void prep_weights(
    const float* __restrict__ theta, const float* __restrict__ eta_inv,
    _Float16* __restrict__ W2t, float* __restrict__ bias)
{
    const int n = blockIdx.x;
    const int t = threadIdx.x;
    const int lane = t & 63, wave = t >> 6;
    __shared__ float red[4];

    float tt = theta[t * 256 + n];
    tt = fminf(fmaxf(tt, -GMAX_), GMAX_);
    if (fabsf(tt) < GMIN_) tt = 0.f;

    float extra = 0.f;
    if (t < 2) {
        extra = theta[(256 + t) * 256 + n];
        extra = fminf(fmaxf(extra, -GMAX_), GMAX_);
        if (fabsf(extra) < GMIN_) extra = 0.f;
    }

    float s = fabsf(tt) + fabsf(extra);
#pragma unroll
    for (int i = 32; i > 0; i >>= 1) s += __shfl_xor(s, i);
    if (lane == 0) red[wave] = s;
    __syncthreads();
    const float inv = 1.0f / (red[0] + red[1] + red[2] + red[3]);

    const float w  = fabsf(tt) * inv;
    const float wp = (tt >= 0.f) ? w : 0.f;
    const float wn = w - wp;
    union { _Float16 h[2]; u32 u; } p;
    p.h[0] = (_Float16)wp;
    p.h[1] = (_Float16)wn;
    *(u32*)((char*)W2t + (size_t)n * 1024 + (size_t)t * 4) = p.u;

    if (t == 0) {
        const float w6  = fabsf(extra) * inv;
        const float wp6 = (extra >= 0.f) ? w6 : 0.f;
        const float wn6 = w6 - wp6;
        const float ei0 = eta_inv[0], ei1 = eta_inv[1], ei2 = eta_inv[2], ei3 = eta_inv[3];
        const float a1  = ei0 + ei1 * tanhf((1.0f - ei2) * ei3);
        bias[n] = wp6 + a1 * wn6;
    }
}

// ---------------------------------------------------------------------------
// GEMM: block = 128 rows x 128 cols, 4 waves stacked over m (wave 32x128).
// B staged per K-half into 64KB LDS via global_load_lds (pre-swizzled src,
// XOR on low-3 16B-slot bits). A direct from global, 2-deep reg prefetch,
// f32 -> {f16(a), f16(ptanh_inv(a))} interleaved pack. 4 barriers total.
// Grid = 256 mblk x 2 nblk = 512 blocks = exactly 2 blocks/CU (LDS-bound).
// ---------------------------------------------------------------------------
__global__ __launch_bounds__(256, 2) void plax_gemm(
    const float* __restrict__ A, const _Float16* __restrict__ W2t,
    const float* __restrict__ bias, const float* __restrict__ eta_act,
    const float* __restrict__ eta_inv, float* __restrict__ out)
{
    __shared__ __align__(16) char Bs[65536];   // [128 cols][256 K-f16], swizzled

    const int t    = threadIdx.x;
    const int bid  = blockIdx.x;
    const int swz  = ((bid & 7) << 6) | (bid >> 3);   // XCD-bijective (512 = 8*64)
    const int mblk = swz >> 1;       // 0..255
    const int nblk = swz & 1;        // 0..1
    const int lane = t & 63, wave = t >> 6;
    const int lr   = lane & 15, lg = lane >> 4;

    const float ei0 = eta_inv[0], ei1 = eta_inv[1];
    const float k2i = 2.0f * eta_inv[3];
    const float c2i = 2.0f * eta_inv[2] * eta_inv[3];

    const int row0 = mblk * 128 + wave * 32;
    const int col0 = nblk * 128;

    const float* ap = A + (size_t)(row0 + lr) * 256 + lg * 4;

    f32x4 acc[2][8] = {};

    // A slice loader: iteration it (0..15) uses f32 cols [it*16 + lg*4 .. +3]
#define LDA(it, dst) do {                                         \
        dst[0] = *(const float4*)(ap + (it) * 16);                \
        dst[1] = *(const float4*)(ap + 4096 + (it) * 16);         \
    } while (0)

    float4 aq0[2], aq1[2], aq2[2];   // 2-deep rotating prefetch (static names)
    LDA(0, aq0);
    LDA(1, aq1);

    const int r_st   = t >> 5;       // stage row sub-index (0..7)
    const int s_phys = t & 31;       // physical 16B slot

#pragma unroll
    for (int it = 0; it < 16; ++it) {
        const int half = it >> 3;
        const int ks   = it & 7;

        if (ks == 0) {
            __syncthreads();         // all waves done reading previous half
#pragma unroll
            for (int i = 0; i < 16; ++i) {
                const int r  = i * 8 + r_st;                       // col-local row
                const int sl = (s_phys & ~7) | ((s_phys ^ r) & 7); // inverse swizzle
                const char* gp = (const char*)W2t
                    + (size_t)(col0 + r) * 1024 + half * 512 + sl * 16;
                __builtin_amdgcn_global_load_lds(
                    (const __attribute__((address_space(1))) u32*)gp,
                    (__attribute__((address_space(3))) u32*)(Bs + i * 4096 + t * 16),
                    16, 0, 0);
            }
            __syncthreads();         // vmcnt(0) drain: staged data visible
        }

        // prefetch A two iterations ahead
        if (it + 2 < 16) {
            if ((it % 3) == 0)      LDA(it + 2, aq2);
            else if ((it % 3) == 1) LDA(it + 2, aq0);
            else                    LDA(it + 2, aq1);
        }

        // current A registers (static rotation)
        float4* acur = ((it % 3) == 0) ? aq0 : ((it % 3) == 1) ? aq1 : aq2;

        // tanh pack: f32x4 -> interleaved [a, aneg] f16x8
        f16x8 af[2];
#pragma unroll
        for (int m = 0; m < 2; ++m) {
            const float4 v = acur[m];
            f16x8 h;
            h[0] = (_Float16)v.x;
            h[1] = (_Float16)fmaf(ei1, tanh_fast2(fmaf(v.x, k2i, -c2i)), ei0);
            h[2] = (_Float16)v.y;
            h[3] = (_Float16)fmaf(ei1, tanh_fast2(fmaf(v.y, k2i, -c2i)), ei0);
            h[4] = (_Float16)v.z;
            h[5] = (_Float16)fmaf(ei1, tanh_fast2(fmaf(v.z, k2i, -c2i)), ei0);
            h[6] = (_Float16)v.w;
            h[7] = (_Float16)fmaf(ei1, tanh_fast2(fmaf(v.w, k2i, -c2i)), ei0);
            af[m] = h;
        }

        // B fragments from swizzled LDS (2-way bank aliasing = free)
        f16x8 bf[8];
#pragma unroll
        for (int n = 0; n < 8; ++n) {
            const int r  = n * 16 + lr;
            const int s  = ks * 4 + lg;
            const int sw = (s & ~7) | ((s ^ r) & 7);
            bf[n] = *(const f16x8*)(Bs + (size_t)r * 512 + sw * 16);
        }

#pragma unroll
        for (int m = 0; m < 2; ++m)
#pragma unroll
            for (int n = 0; n < 8; ++n)
                acc[m][n] = __builtin_amdgcn_mfma_f32_16x16x32_f16(
                    af[m], bf[n], acc[m][n], 0, 0, 0);
    }
#undef LDA

    // ---- epilogue: z = acc + bias ; out = ptanh_act(z) ----
    const float ea0 = eta_act[0], ea1 = eta_act[1];
    const float k2a = 2.0f * eta_act[3];
    const float c2a = 2.0f * eta_act[2] * eta_act[3];

    float bc[8];
#pragma unroll
    for (int n = 0; n < 8; ++n) bc[n] = bias[col0 + n * 16 + lr];

#pragma unroll
    for (int m = 0; m < 2; ++m) {
        const int rgb = row0 + m * 16 + lg * 4;
#pragma unroll
        for (int n = 0; n < 8; ++n) {
            const int cg = col0 + n * 16 + lr;
#pragma unroll
            for (int j = 0; j < 4; ++j) {
                const float z = acc[m][n][j] + bc[n];
                out[(size_t)(rgb + j) * 256 + cg] =
                    fmaf(ea1, tanh_fast2(fmaf(z, k2a, -c2a)), ea0);
            }
        }
    }
}

// ---------------------------------------------------------------------------
extern "C" void kernel_launch(void* const* d_in, const int* in_sizes, int n_in,
                              void* d_out, int out_size, void* d_ws, size_t ws_size,
                              hipStream_t stream) {
    (void)in_sizes; (void)n_in; (void)out_size; (void)ws_size;
    const float* a       = (const float*)d_in[0];
    const float* theta   = (const float*)d_in[1];
    const float* eta_act = (const float*)d_in[2];
    const float* eta_inv = (const float*)d_in[3];
    float* out = (float*)d_out;

    _Float16* W2t  = (_Float16*)d_ws;                        // 256 KiB
    float*    bias = (float*)((char*)d_ws + 256 * 512 * 2);  // 1 KiB

    prep_weights<<<256, 256, 0, stream>>>(theta, eta_inv, W2t, bias);
    plax_gemm<<<512, 256, 0, stream>>>(a, W2t, bias, eta_act, eta_inv, out);
}